// Round 15
// baseline (356.111 us; speedup 1.0000x reference)
//
#include <hip/hip_runtime.h>
#include <cstdint>
#include <cmath>

#define NB 256      // graphs (B)
#define MM 256      // nodes per graph
#define NN (NB*MM)  // 65536 nodes
#define KNN 15
#define FIN 7
#define CC 128
#define CCP 136     // padded LDS row stride (shorts)
#define C2 768
#define NL 3
#define FINF 3.4e38f

__device__ __forceinline__ float lrelu(float v){ return v > 0.f ? v : 0.01f*v; }

__device__ __forceinline__ unsigned short f2bf(float f){
  unsigned u = __float_as_uint(f);
  return (unsigned short)((u + 0x7FFFu + ((u >> 16) & 1u)) >> 16);
}
__device__ __forceinline__ float bf2f(unsigned short h){
  return __uint_as_float(((unsigned)h) << 16);
}

__device__ __forceinline__ int mbcnt64(unsigned long long m){
  return (int)__builtin_amdgcn_mbcnt_hi((unsigned)(m >> 32),
              __builtin_amdgcn_mbcnt_lo((unsigned)m, 0u));
}

typedef short bf16x8 __attribute__((ext_vector_type(8)));
typedef float f32x4  __attribute__((ext_vector_type(4)));

// ---------------------------------------------------------------- kNN -------
// Radix-select (R9: 143 -> 58 us). R15: 2-way split (~28 us each) so the
// rocprof top-5 can see every dispatch >= 28 us (knn rows have masked the
// leaderboard for 6 rounds; accounting has a ~150 us unattributed gap).
__global__ __launch_bounds__(256) void knn_kernel(const float* __restrict__ x,
                                                  int* __restrict__ knn,
                                                  int base){
  __shared__ float4 pos[MM];
  __shared__ float  sq[MM];
  __shared__ unsigned skey[4][16];
  __shared__ int      sidx[4][16];
  const int bb = blockIdx.x + base;
  const int g = bb >> 6;
  const int t = threadIdx.x;
  const float* xr = x + (size_t)(g*MM + t)*FIN;
  float4 p = make_float4(xr[0], xr[1], xr[2], xr[3]);
  pos[t] = p;
  sq[t]  = p.x*p.x + p.y*p.y + p.z*p.z + p.w*p.w;
  __syncthreads();

  const int i    = (bb & 63)*4 + (t >> 6);
  const int wv   = t >> 6;
  const int lane = t & 63;
  const float4 pi = pos[i];
  const float  sqi = sq[i];

  unsigned key[4];
#pragma unroll
  for (int q=0;q<4;q++){
    int j = q*64 + lane;
    float4 pj = pos[j];
    float dot = pi.x*pj.x + pi.y*pj.y + pi.z*pj.z + pi.w*pj.w;
    float d2  = sqi + sq[j] - 2.f*dot;
    unsigned u = __float_as_uint(d2);
    u = ((int)u < 0) ? ~u : (u ^ 0x80000000u);
    key[q] = (j == i) ? 0xFFFFFFFFu : u;
  }

  unsigned prefix = 0u;
#pragma unroll
  for (int bit=31; bit>=0; --bit){
    unsigned trial = prefix | (1u << bit);
    int c = __popcll(__ballot(key[0] < trial))
          + __popcll(__ballot(key[1] < trial))
          + __popcll(__ballot(key[2] < trial))
          + __popcll(__ballot(key[3] < trial));
    if (c < KNN) prefix = trial;
  }
  const unsigned K = prefix;

  int c_lt = __popcll(__ballot(key[0] < K)) + __popcll(__ballot(key[1] < K))
           + __popcll(__ballot(key[2] < K)) + __popcll(__ballot(key[3] < K));
  int need = KNN - c_lt;
  bool w[4];
  int eqbase = 0;
#pragma unroll
  for (int q=0;q<4;q++){
    unsigned long long em = __ballot(key[q] == K);
    int gr = eqbase + mbcnt64(em);
    w[q] = (key[q] < K) || ((key[q] == K) && (gr < need));
    eqbase += __popcll(em);
  }

  int base2 = 0;
#pragma unroll
  for (int q=0;q<4;q++){
    unsigned long long wm = __ballot(w[q]);
    int rk = mbcnt64(wm);
    if (w[q]){ skey[wv][base2+rk] = key[q]; sidx[wv][base2+rk] = q*64 + lane; }
    base2 += __popcll(wm);
  }
  __builtin_amdgcn_wave_barrier();

  if (lane < KNN){
    unsigned mk = skey[wv][lane]; int mi = sidx[wv][lane];
    int r = 0;
#pragma unroll
    for (int m=0;m<KNN;m++){
      unsigned ok = skey[wv][m]; int oi = sidx[wv][m];
      r += (ok < mk || (ok == mk && oi < mi)) ? 1 : 0;
    }
    knn[(size_t)(g*MM + i)*KNN + r] = g*MM + mi;
  }
}

// -------------------- layer 1 fused (agg7 x2 + conv1 + pool0) ---------------
__global__ __launch_bounds__(256) void layer1_fused_kernel(
    const float* __restrict__ x, const int* __restrict__ knn,
    const float* __restrict__ W, const float* __restrict__ b,
    unsigned short* __restrict__ out, float* __restrict__ gf){
  __shared__ float feat[MM][24];
  __shared__ float smean[4][CC], smax[4][CC];
  const int g = blockIdx.x, tid = threadIdx.x;
  for (int e=tid; e<MM*FIN; e+=256){
    int nn = e / FIN, f = e - nn*FIN;
    feat[nn][f] = x[(size_t)g*MM*FIN + e];
  }
  __syncthreads();
  {
    const int nn = tid;
    const int* kn = knn + (size_t)(g*MM + nn)*KNN;
    int loc[KNN];
#pragma unroll
    for (int k=0;k<KNN;k++) loc[k] = kn[k] & (MM-1);
#pragma unroll
    for (int c=0;c<FIN;c++){
      float s = 0.f;
#pragma unroll
      for (int k=0;k<KNN;k++) s += feat[loc[k]][c];
      feat[nn][FIN + c] = s * (1.f/15.f);
    }
    __syncthreads();
#pragma unroll
    for (int c=0;c<FIN;c++){
      float s = 0.f;
#pragma unroll
      for (int k=0;k<KNN;k++) s += feat[loc[k]][FIN + c];
      feat[nn][2*FIN + c] = s * (1.f/15.f);
    }
  }
  __syncthreads();
  const int c    = tid & 127;
  const int half = tid >> 7;
  float wcol[3*FIN];
#pragma unroll
  for (int t2=0;t2<3*FIN;t2++) wcol[t2] = W[t2*CC + c];
  const float bc = b[c];
  float ps[2] = {0.f, 0.f};
  float pm[2] = {-FINF, -FINF};
  for (int nn=half*128; nn<half*128+128; ++nn){
    float4 f0 = *(const float4*)(&feat[nn][0]);
    float4 f1 = *(const float4*)(&feat[nn][4]);
    float4 f2 = *(const float4*)(&feat[nn][8]);
    float4 f3 = *(const float4*)(&feat[nn][12]);
    float4 f4 = *(const float4*)(&feat[nn][16]);
    float4 f5 = *(const float4*)(&feat[nn][20]);
    float fv[21] = {f0.x,f0.y,f0.z,f0.w, f1.x,f1.y,f1.z,f1.w,
                    f2.x,f2.y,f2.z,f2.w, f3.x,f3.y,f3.z,f3.w,
                    f4.x,f4.y,f4.z,f4.w, f5.x};
    float acc = bc;
#pragma unroll
    for (int t2=0;t2<3*FIN;t2++) acc += fv[t2]*wcol[t2];
    unsigned short o = f2bf(lrelu(acc));
    out[(size_t)(g*MM + nn)*CC + c] = o;
    float v = bf2f(o);
    int lg = (nn >> 6) & 1;
    ps[lg] += v; pm[lg] = fmaxf(pm[lg], v);
  }
  smean[half*2+0][c] = ps[0]; smean[half*2+1][c] = ps[1];
  smax [half*2+0][c] = pm[0]; smax [half*2+1][c] = pm[1];
  __syncthreads();
  if (tid < 128){
    float s  = smean[0][c] + smean[1][c] + smean[2][c] + smean[3][c];
    float mx = fmaxf(fmaxf(smax[0][c], smax[1][c]), fmaxf(smax[2][c], smax[3][c]));
    gf[(size_t)g*C2 + c]      = s * (1.f/MM);
    gf[(size_t)g*C2 + CC + c] = mx;
  }
}

// ----------------------------------------------- pack W into B-frag order ---
__global__ void packW_kernel(const float* __restrict__ W2src,
                             const float* __restrict__ W3src,
                             unsigned short* __restrict__ W2dst,
                             unsigned short* __restrict__ W3dst){
  int idx = blockIdx.x*256 + threadIdx.x;
  if (idx >= 2*3*CC*CC) return;
  const float* Wsrc = (idx < 3*CC*CC) ? W2src : W3src;
  unsigned short* Wdst = (idx < 3*CC*CC) ? W2dst : W3dst;
  int e = (idx < 3*CC*CC) ? idx : idx - 3*CC*CC;
  int kg = e >> 7;
  int n  = e & 127;
  int ck = kg >> 5, q = (kg >> 3) & 3, j = kg & 7;
  Wdst[(((ck*4 + q)*CC) + n)*8 + j] = f2bf(Wsrc[e]);
}

// ---------------------- exact agg128 arithmetic, LDS->LDS (1024 threads) ----
// kn now read from LDS (staged once) instead of global each phase.
__device__ __forceinline__ void agg_lds(const unsigned short* __restrict__ src,
                                        unsigned short* __restrict__ dst,
                                        const int* __restrict__ skn,
                                        int tid){
  for (int it=0; it<4; ++it){
    int idx = it*1024 + tid;
    int nn  = idx >> 4;
    int c8  = (idx & 15) * 8;
    const int* kn = skn + nn*KNN;
    float s[8];
#pragma unroll
    for (int e=0;e<8;e++) s[e]=0.f;
#pragma unroll
    for (int k=0;k<KNN;k++){
      int loc = kn[k] & (MM-1);
      uint4 r = *(const uint4*)(src + loc*CCP + c8);
      s[0] += __uint_as_float(r.x << 16); s[1] += __uint_as_float(r.x & 0xFFFF0000u);
      s[2] += __uint_as_float(r.y << 16); s[3] += __uint_as_float(r.y & 0xFFFF0000u);
      s[4] += __uint_as_float(r.z << 16); s[5] += __uint_as_float(r.z & 0xFFFF0000u);
      s[6] += __uint_as_float(r.w << 16); s[7] += __uint_as_float(r.w & 0xFFFF0000u);
    }
    const float inv = 1.f/15.f;
    uint4 o;
    o.x = (unsigned)f2bf(s[0]*inv) | ((unsigned)f2bf(s[1]*inv) << 16);
    o.y = (unsigned)f2bf(s[2]*inv) | ((unsigned)f2bf(s[3]*inv) << 16);
    o.z = (unsigned)f2bf(s[4]*inv) | ((unsigned)f2bf(s[5]*inv) << 16);
    o.w = (unsigned)f2bf(s[6]*inv) | ((unsigned)f2bf(s[7]*inv) << 16);
    *(uint4*)(dst + nn*CCP + c8) = o;
  }
}

// ------------- conv layer 2/3 fully fused (agg + agg + MFMA + pool) --------
// R15: graph's knn table (15 KB) staged to LDS once -> kills 2x960 wave-level
// global index loads. Total static LDS 158.7 KB (< 160 KiB). Index values
// identical, arithmetic order unchanged -> bit-identical output.
__global__ __launch_bounds__(1024) void conv_fused_kernel(
    const unsigned short* __restrict__ hin,
    const int* __restrict__ knn,
    const unsigned short* __restrict__ Wpk,
    const float* __restrict__ bias,
    unsigned short* __restrict__ hout,
    float* __restrict__ gf, int poff){
  __shared__ unsigned short bufh[MM*CCP];   // 69632 B
  __shared__ unsigned short bufa[MM*CCP];   // 69632 B
  __shared__ int skn[MM*KNN];               // 15360 B
  __shared__ float smean[4][CC], smax[4][CC];
  const int g   = blockIdx.x;
  const int tid = threadIdx.x;

  {
    const uint4* src = (const uint4*)(hin + (size_t)g*MM*CC);
    for (int e=tid; e<MM*CC/8; e+=1024){
      int row = e >> 4, ch = e & 15;
      *(uint4*)(bufh + row*CCP + ch*8) = src[e];
    }
    const int* kg = knn + (size_t)g*MM*KNN;
    for (int e=tid; e<MM*KNN; e+=1024) skn[e] = kg[e];
  }
  __syncthreads();

  agg_lds(bufh, bufa, skn, tid);   // a1 = agg(h)
  __syncthreads();

  const int wv   = tid >> 6, lane = tid & 63;
  const int n    = lane & 15, q = lane >> 4;
  const int rows0 = (wv & 7)*32;
  const int cols0 = (wv >> 3)*64;

  f32x4 acc[2][4];
#pragma unroll
  for (int i=0;i<2;i++)
#pragma unroll
    for (int t=0;t<4;t++) acc[i][t] = (f32x4){0.f,0.f,0.f,0.f};

#pragma unroll
  for (int ck=0; ck<8; ck++){
    const unsigned short* A = (ck < 4) ? bufh : bufa;
    const int kc = ck & 3;
    const unsigned short* ab = A + (rows0 + n)*CCP + kc*32 + q*8;
    bf16x8 af[2];
#pragma unroll
    for (int i=0;i<2;i++) af[i] = *(const bf16x8*)(ab + i*16*CCP);
    const unsigned short* wb = Wpk + ((size_t)(ck*4 + q)*CC + cols0 + n)*8;
    bf16x8 bf[4];
#pragma unroll
    for (int t=0;t<4;t++) bf[t] = *(const bf16x8*)(wb + t*16*8);
#pragma unroll
    for (int i=0;i<2;i++)
#pragma unroll
      for (int t=0;t<4;t++)
        acc[i][t] = __builtin_amdgcn_mfma_f32_16x16x32_bf16(af[i], bf[t], acc[i][t], 0, 0, 0);
  }
  __syncthreads();

  agg_lds(bufa, bufh, skn, tid);   // a2 = agg(a1), overwrites bufh
  __syncthreads();

#pragma unroll
  for (int ck=8; ck<12; ck++){
    const int kc = ck & 3;
    const unsigned short* ab = bufh + (rows0 + n)*CCP + kc*32 + q*8;
    bf16x8 af[2];
#pragma unroll
    for (int i=0;i<2;i++) af[i] = *(const bf16x8*)(ab + i*16*CCP);
    const unsigned short* wb = Wpk + ((size_t)(ck*4 + q)*CC + cols0 + n)*8;
    bf16x8 bf[4];
#pragma unroll
    for (int t=0;t<4;t++) bf[t] = *(const bf16x8*)(wb + t*16*8);
#pragma unroll
    for (int i=0;i<2;i++)
#pragma unroll
      for (int t=0;t<4;t++)
        acc[i][t] = __builtin_amdgcn_mfma_f32_16x16x32_bf16(af[i], bf[t], acc[i][t], 0, 0, 0);
  }

  float bv[4];
#pragma unroll
  for (int t=0;t<4;t++) bv[t] = bias[cols0 + t*16 + n];
#pragma unroll
  for (int i=0;i<2;i++){
#pragma unroll
    for (int t=0;t<4;t++){
#pragma unroll
      for (int r=0;r<4;r++){
        int row = rows0 + i*16 + q*4 + r;
        int col = cols0 + t*16 + n;
        unsigned short o = f2bf(lrelu(acc[i][t][r] + bv[t]));
        hout[(size_t)(g*MM + row)*CC + col] = o;
        bufa[row*CCP + col] = o;
      }
    }
  }
  __syncthreads();

  {
    const int c = tid & 127, grp = (tid >> 7) & 3;
    if (tid < 512){
      float s = 0.f, mx = -FINF;
      for (int m=grp*64; m<grp*64+64; m++){
        float v = bf2f(bufa[m*CCP + c]);
        s += v; mx = fmaxf(mx, v);
      }
      smean[grp][c] = s; smax[grp][c] = mx;
    }
    __syncthreads();
    if (tid < 128){
      float s  = smean[0][c] + smean[1][c] + smean[2][c] + smean[3][c];
      float mx = fmaxf(fmaxf(smax[0][c], smax[1][c]), fmaxf(smax[2][c], smax[3][c]));
      gf[(size_t)g*C2 + poff + c]      = s * (1.f/MM);
      gf[(size_t)g*C2 + poff + CC + c] = mx;
    }
  }
}

// ------------------------------------------------------ batchnorm (stats) ---
__global__ __launch_bounds__(256) void bnstats_kernel(const float* __restrict__ g,
                                                      const float* __restrict__ gamma,
                                                      const float* __restrict__ beta,
                                                      float* __restrict__ scb,
                                                      float* __restrict__ shb){
  __shared__ float ssum[4][64], ssq[4][64];
  const int cl = threadIdx.x & 63, rg = threadIdx.x >> 6;
  const int c  = blockIdx.x*64 + cl;
  float s=0.f, q=0.f;
  for (int r=rg*64; r<rg*64+64; r++){
    float v = g[(size_t)r*C2 + c];
    s += v; q += v*v;
  }
  ssum[rg][cl]=s; ssq[rg][cl]=q;
  __syncthreads();
  if (rg == 0){
    s = ssum[0][cl]+ssum[1][cl]+ssum[2][cl]+ssum[3][cl];
    q = ssq [0][cl]+ssq [1][cl]+ssq [2][cl]+ssq [3][cl];
    float mu  = s * (1.f/NB);
    float var = q * (1.f/NB) - mu*mu;
    float sc  = rsqrtf(var + 1e-5f) * gamma[c];
    scb[c] = sc;
    shb[c] = beta[c] - mu*sc;
  }
}

// -------------------------------------------------- MLP (wave-K-split GEMM) -
__global__ __launch_bounds__(256) void mlp_gemm_kernel(
    const float* __restrict__ A, const float* __restrict__ W,
    const float* __restrict__ bias,
    const float* __restrict__ scb, const float* __restrict__ shb, int affine,
    float* __restrict__ out){
  __shared__ float Ws[4][32][64];
  __shared__ float At[4][32][10];
  const int tid  = threadIdx.x;
  const int ks   = tid >> 6, lane = tid & 63;
  const int colq = lane & 15, rp = lane >> 4;
  const int col0 = blockIdx.x * 64;
  const int row0 = blockIdx.y * 8;

  float a00=0.f,a01=0.f,a02=0.f,a03=0.f;
  float a10=0.f,a11=0.f,a12=0.f,a13=0.f;

  for (int kt=0; kt<6; kt++){
    const int kc0 = ks*192 + kt*32;
#pragma unroll
    for (int i=0;i<8;i++){
      int idx = i*256 + lane*4;
      int kr = idx >> 6, cc = idx & 63;
      *(float4*)(&Ws[ks][kr][cc]) =
          *(const float4*)(W + (size_t)(kc0+kr)*C2 + col0 + cc);
    }
    {
      int row = lane >> 3, kq = lane & 7;
      float4 a = *(const float4*)(A + (size_t)(row0+row)*C2 + kc0 + kq*4);
      if (affine){
        float4 s4 = *(const float4*)(scb + kc0 + kq*4);
        float4 h4 = *(const float4*)(shb + kc0 + kq*4);
        a.x = a.x*s4.x + h4.x; a.y = a.y*s4.y + h4.y;
        a.z = a.z*s4.z + h4.z; a.w = a.w*s4.w + h4.w;
      }
      At[ks][kq*4+0][row] = a.x;
      At[ks][kq*4+1][row] = a.y;
      At[ks][kq*4+2][row] = a.z;
      At[ks][kq*4+3][row] = a.w;
    }
    __builtin_amdgcn_wave_barrier();
#pragma unroll 8
    for (int kk=0;kk<32;kk++){
      float4 w = *(const float4*)(&Ws[ks][kk][colq*4]);
      float b0 = At[ks][kk][rp*2+0];
      float b1 = At[ks][kk][rp*2+1];
      a00 += b0*w.x; a01 += b0*w.y; a02 += b0*w.z; a03 += b0*w.w;
      a10 += b1*w.x; a11 += b1*w.y; a12 += b1*w.z; a13 += b1*w.w;
    }
    __builtin_amdgcn_wave_barrier();
  }

  if (ks > 0){
    float* part = &Ws[ks][0][0];
    *(float4*)(part + (rp*2+0)*64 + colq*4) = make_float4(a00,a01,a02,a03);
    *(float4*)(part + (rp*2+1)*64 + colq*4) = make_float4(a10,a11,a12,a13);
  }
  __syncthreads();
  if (ks == 0){
    float4 bv = *(const float4*)(bias + col0 + colq*4);
    float accr[2][4] = {{a00,a01,a02,a03},{a10,a11,a12,a13}};
#pragma unroll
    for (int r=0;r<2;r++){
      int off = (rp*2+r)*64 + colq*4;
      float4 p1 = *(const float4*)(&Ws[1][0][0] + off);
      float4 p2 = *(const float4*)(&Ws[2][0][0] + off);
      float4 p3 = *(const float4*)(&Ws[3][0][0] + off);
      float4 o;
      o.x = lrelu(accr[r][0] + p1.x + p2.x + p3.x + bv.x);
      o.y = lrelu(accr[r][1] + p1.y + p2.y + p3.y + bv.y);
      o.z = lrelu(accr[r][2] + p1.z + p2.z + p3.z + bv.z);
      o.w = lrelu(accr[r][3] + p1.w + p2.w + p3.w + bv.w);
      *(float4*)(out + (size_t)(row0 + rp*2 + r)*C2 + col0 + colq*4) = o;
    }
  }
}

// ------------------------------------------------------------- final layer --
__global__ __launch_bounds__(64) void final_kernel(const float* __restrict__ g,
                                                   const float* __restrict__ Wo,
                                                   const float* __restrict__ bo,
                                                   float* __restrict__ out){
  int i = blockIdx.x*64 + threadIdx.x;
  if (i >= NB*NL) return;
  int r = i / NL, c = i - r*NL;
  const float* gr = g + (size_t)r*C2;
  float acc = bo[c];
  for (int k=0;k<C2;k++) acc += gr[k]*Wo[k*NL + c];
  if (c < 2) acc = tanhf(acc);
  out[i] = acc;
}

// ------------------------------------------------------------------ launch --
extern "C" void kernel_launch(void* const* d_in, const int* in_sizes, int n_in,
                              void* d_out, int out_size, void* d_ws, size_t ws_size,
                              hipStream_t stream){
  const float* x   = (const float*)d_in[0];
  const float* Wc1 = (const float*)d_in[1];
  const float* bc1 = (const float*)d_in[2];
  const float* Wc2 = (const float*)d_in[3];
  const float* bc2 = (const float*)d_in[4];
  const float* Wc3 = (const float*)d_in[5];
  const float* bc3 = (const float*)d_in[6];
  const float* bng = (const float*)d_in[7];
  const float* bnb = (const float*)d_in[8];
  const float* W1  = (const float*)d_in[9];
  const float* b1  = (const float*)d_in[10];
  const float* W2  = (const float*)d_in[11];
  const float* b2  = (const float*)d_in[12];
  const float* W3  = (const float*)d_in[13];
  const float* b3  = (const float*)d_in[14];
  const float* W4  = (const float*)d_in[15];
  const float* b4  = (const float*)d_in[16];
  const float* W5  = (const float*)d_in[17];
  const float* b5  = (const float*)d_in[18];
  const float* Wo  = (const float*)d_in[19];
  const float* bo  = (const float*)d_in[20];

  char* ws = (char*)d_ws;
  size_t o = 0;
  int*            knn  = (int*)           (ws + o); o += (size_t)NN*KNN*4;
  unsigned short* h0   = (unsigned short*)(ws + o); o += (size_t)NN*CC*2;
  unsigned short* h3   = (unsigned short*)(ws + o); o += (size_t)NN*CC*2;
  float*          gf   = (float*)         (ws + o); o += (size_t)NB*C2*4;
  float*          gt   = (float*)         (ws + o); o += (size_t)NB*C2*4;
  unsigned short* Wpk2 = (unsigned short*)(ws + o); o += (size_t)3*CC*CC*2;
  unsigned short* Wpk3 = (unsigned short*)(ws + o); o += (size_t)3*CC*CC*2;
  float*          scb  = (float*)         (ws + o); o += (size_t)C2*4;
  float*          shb  = (float*)         (ws + o); o += (size_t)C2*4;

  knn_kernel<<<NB*32, 256, 0, stream>>>(x, knn, 0);
  knn_kernel<<<NB*32, 256, 0, stream>>>(x, knn, NB*32);
  packW_kernel<<<384, 256, 0, stream>>>(Wc2, Wc3, Wpk2, Wpk3);

  layer1_fused_kernel<<<NB, 256, 0, stream>>>(x, knn, Wc1, bc1, h0, gf);
  conv_fused_kernel<<<NB, 1024, 0, stream>>>(h0, knn, Wpk2, bc2, h3, gf, 2*CC);
  conv_fused_kernel<<<NB, 1024, 0, stream>>>(h3, knn, Wpk3, bc3, h0, gf, 4*CC);

  bnstats_kernel<<<12, 256, 0, stream>>>(gf, bng, bnb, scb, shb);

  dim3 mgrid(12, 32);
  mlp_gemm_kernel<<<mgrid, 256, 0, stream>>>(gf, W1, b1, scb, shb, 1, gt);
  mlp_gemm_kernel<<<mgrid, 256, 0, stream>>>(gt, W2, b2, nullptr, nullptr, 0, gf);
  mlp_gemm_kernel<<<mgrid, 256, 0, stream>>>(gf, W3, b3, nullptr, nullptr, 0, gt);
  mlp_gemm_kernel<<<mgrid, 256, 0, stream>>>(gt, W4, b4, nullptr, nullptr, 0, gf);
  mlp_gemm_kernel<<<mgrid, 256, 0, stream>>>(gf, W5, b5, nullptr, nullptr, 0, gt);

  final_kernel<<<12, 64, 0, stream>>>(gt, Wo, bo, (float*)d_out);
}

// Round 16
// 347.147 us; speedup vs baseline: 1.0258x; 1.0258x over previous
//
#include <hip/hip_runtime.h>
#include <cstdint>
#include <cmath>

#define NB 256      // graphs (B)
#define MM 256      // nodes per graph
#define NN (NB*MM)  // 65536 nodes
#define KNN 15
#define FIN 7
#define CC 128
#define CCP 136     // padded LDS row stride (shorts)
#define C2 768
#define NL 3
#define FINF 3.4e38f

__device__ __forceinline__ float lrelu(float v){ return v > 0.f ? v : 0.01f*v; }

__device__ __forceinline__ unsigned short f2bf(float f){
  unsigned u = __float_as_uint(f);
  return (unsigned short)((u + 0x7FFFu + ((u >> 16) & 1u)) >> 16);
}
__device__ __forceinline__ float bf2f(unsigned short h){
  return __uint_as_float(((unsigned)h) << 16);
}

__device__ __forceinline__ int mbcnt64(unsigned long long m){
  return (int)__builtin_amdgcn_mbcnt_hi((unsigned)(m >> 32),
              __builtin_amdgcn_mbcnt_lo((unsigned)m, 0u));
}

typedef short bf16x8 __attribute__((ext_vector_type(8)));
typedef float f32x4  __attribute__((ext_vector_type(4)));

// ---------------------------------------------------------------- kNN -------
// Radix-select (R9: 143 -> 58 us). Single dispatch (R15's 2-way split cost
// ~2.3 us and its diagnostic job is done: everything else is < 41 us).
__global__ __launch_bounds__(256) void knn_kernel(const float* __restrict__ x,
                                                  int* __restrict__ knn){
  __shared__ float4 pos[MM];
  __shared__ float  sq[MM];
  __shared__ unsigned skey[4][16];
  __shared__ int      sidx[4][16];
  const int g = blockIdx.x >> 6;
  const int t = threadIdx.x;
  const float* xr = x + (size_t)(g*MM + t)*FIN;
  float4 p = make_float4(xr[0], xr[1], xr[2], xr[3]);
  pos[t] = p;
  sq[t]  = p.x*p.x + p.y*p.y + p.z*p.z + p.w*p.w;
  __syncthreads();

  const int i    = (blockIdx.x & 63)*4 + (t >> 6);
  const int wv   = t >> 6;
  const int lane = t & 63;
  const float4 pi = pos[i];
  const float  sqi = sq[i];

  unsigned key[4];
#pragma unroll
  for (int q=0;q<4;q++){
    int j = q*64 + lane;
    float4 pj = pos[j];
    float dot = pi.x*pj.x + pi.y*pj.y + pi.z*pj.z + pi.w*pj.w;
    float d2  = sqi + sq[j] - 2.f*dot;
    unsigned u = __float_as_uint(d2);
    u = ((int)u < 0) ? ~u : (u ^ 0x80000000u);
    key[q] = (j == i) ? 0xFFFFFFFFu : u;
  }

  unsigned prefix = 0u;
#pragma unroll
  for (int bit=31; bit>=0; --bit){
    unsigned trial = prefix | (1u << bit);
    int c = __popcll(__ballot(key[0] < trial))
          + __popcll(__ballot(key[1] < trial))
          + __popcll(__ballot(key[2] < trial))
          + __popcll(__ballot(key[3] < trial));
    if (c < KNN) prefix = trial;
  }
  const unsigned K = prefix;

  int c_lt = __popcll(__ballot(key[0] < K)) + __popcll(__ballot(key[1] < K))
           + __popcll(__ballot(key[2] < K)) + __popcll(__ballot(key[3] < K));
  int need = KNN - c_lt;
  bool w[4];
  int eqbase = 0;
#pragma unroll
  for (int q=0;q<4;q++){
    unsigned long long em = __ballot(key[q] == K);
    int gr = eqbase + mbcnt64(em);
    w[q] = (key[q] < K) || ((key[q] == K) && (gr < need));
    eqbase += __popcll(em);
  }

  int base2 = 0;
#pragma unroll
  for (int q=0;q<4;q++){
    unsigned long long wm = __ballot(w[q]);
    int rk = mbcnt64(wm);
    if (w[q]){ skey[wv][base2+rk] = key[q]; sidx[wv][base2+rk] = q*64 + lane; }
    base2 += __popcll(wm);
  }
  __builtin_amdgcn_wave_barrier();

  if (lane < KNN){
    unsigned mk = skey[wv][lane]; int mi = sidx[wv][lane];
    int r = 0;
#pragma unroll
    for (int m=0;m<KNN;m++){
      unsigned ok = skey[wv][m]; int oi = sidx[wv][m];
      r += (ok < mk || (ok == mk && oi < mi)) ? 1 : 0;
    }
    knn[(size_t)(g*MM + i)*KNN + r] = g*MM + mi;
  }
}

// -------------------- layer 1 fused (agg7 x2 + conv1 + pool0) ---------------
__global__ __launch_bounds__(256) void layer1_fused_kernel(
    const float* __restrict__ x, const int* __restrict__ knn,
    const float* __restrict__ W, const float* __restrict__ b,
    unsigned short* __restrict__ out, float* __restrict__ gf){
  __shared__ float feat[MM][24];
  __shared__ float smean[4][CC], smax[4][CC];
  const int g = blockIdx.x, tid = threadIdx.x;
  for (int e=tid; e<MM*FIN; e+=256){
    int nn = e / FIN, f = e - nn*FIN;
    feat[nn][f] = x[(size_t)g*MM*FIN + e];
  }
  __syncthreads();
  {
    const int nn = tid;
    const int* kn = knn + (size_t)(g*MM + nn)*KNN;
    int loc[KNN];
#pragma unroll
    for (int k=0;k<KNN;k++) loc[k] = kn[k] & (MM-1);
#pragma unroll
    for (int c=0;c<FIN;c++){
      float s = 0.f;
#pragma unroll
      for (int k=0;k<KNN;k++) s += feat[loc[k]][c];
      feat[nn][FIN + c] = s * (1.f/15.f);
    }
    __syncthreads();
#pragma unroll
    for (int c=0;c<FIN;c++){
      float s = 0.f;
#pragma unroll
      for (int k=0;k<KNN;k++) s += feat[loc[k]][FIN + c];
      feat[nn][2*FIN + c] = s * (1.f/15.f);
    }
  }
  __syncthreads();
  const int c    = tid & 127;
  const int half = tid >> 7;
  float wcol[3*FIN];
#pragma unroll
  for (int t2=0;t2<3*FIN;t2++) wcol[t2] = W[t2*CC + c];
  const float bc = b[c];
  float ps[2] = {0.f, 0.f};
  float pm[2] = {-FINF, -FINF};
  for (int nn=half*128; nn<half*128+128; ++nn){
    float4 f0 = *(const float4*)(&feat[nn][0]);
    float4 f1 = *(const float4*)(&feat[nn][4]);
    float4 f2 = *(const float4*)(&feat[nn][8]);
    float4 f3 = *(const float4*)(&feat[nn][12]);
    float4 f4 = *(const float4*)(&feat[nn][16]);
    float4 f5 = *(const float4*)(&feat[nn][20]);
    float fv[21] = {f0.x,f0.y,f0.z,f0.w, f1.x,f1.y,f1.z,f1.w,
                    f2.x,f2.y,f2.z,f2.w, f3.x,f3.y,f3.z,f3.w,
                    f4.x,f4.y,f4.z,f4.w, f5.x};
    float acc = bc;
#pragma unroll
    for (int t2=0;t2<3*FIN;t2++) acc += fv[t2]*wcol[t2];
    unsigned short o = f2bf(lrelu(acc));
    out[(size_t)(g*MM + nn)*CC + c] = o;
    float v = bf2f(o);
    int lg = (nn >> 6) & 1;
    ps[lg] += v; pm[lg] = fmaxf(pm[lg], v);
  }
  smean[half*2+0][c] = ps[0]; smean[half*2+1][c] = ps[1];
  smax [half*2+0][c] = pm[0]; smax [half*2+1][c] = pm[1];
  __syncthreads();
  if (tid < 128){
    float s  = smean[0][c] + smean[1][c] + smean[2][c] + smean[3][c];
    float mx = fmaxf(fmaxf(smax[0][c], smax[1][c]), fmaxf(smax[2][c], smax[3][c]));
    gf[(size_t)g*C2 + c]      = s * (1.f/MM);
    gf[(size_t)g*C2 + CC + c] = mx;
  }
}

// ----------------------------------------------- pack W into B-frag order ---
__global__ void packW_kernel(const float* __restrict__ W2src,
                             const float* __restrict__ W3src,
                             unsigned short* __restrict__ W2dst,
                             unsigned short* __restrict__ W3dst){
  int idx = blockIdx.x*256 + threadIdx.x;
  if (idx >= 2*3*CC*CC) return;
  const float* Wsrc = (idx < 3*CC*CC) ? W2src : W3src;
  unsigned short* Wdst = (idx < 3*CC*CC) ? W2dst : W3dst;
  int e = (idx < 3*CC*CC) ? idx : idx - 3*CC*CC;
  int kg = e >> 7;
  int n  = e & 127;
  int ck = kg >> 5, q = (kg >> 3) & 3, j = kg & 7;
  Wdst[(((ck*4 + q)*CC) + n)*8 + j] = f2bf(Wsrc[e]);
}

// ---------------------- exact agg128 arithmetic, LDS->LDS (1024 threads) ----
// kn from global (R15's LDS staging of kn was neutral-to-negative; reverted).
__device__ __forceinline__ void agg_lds(const unsigned short* __restrict__ src,
                                        unsigned short* __restrict__ dst,
                                        const int* __restrict__ kn_graph,
                                        int tid){
  for (int it=0; it<4; ++it){
    int idx = it*1024 + tid;
    int nn  = idx >> 4;
    int c8  = (idx & 15) * 8;
    const int* kn = kn_graph + nn*KNN;
    float s[8];
#pragma unroll
    for (int e=0;e<8;e++) s[e]=0.f;
#pragma unroll
    for (int k=0;k<KNN;k++){
      int loc = kn[k] & (MM-1);
      uint4 r = *(const uint4*)(src + loc*CCP + c8);
      s[0] += __uint_as_float(r.x << 16); s[1] += __uint_as_float(r.x & 0xFFFF0000u);
      s[2] += __uint_as_float(r.y << 16); s[3] += __uint_as_float(r.y & 0xFFFF0000u);
      s[4] += __uint_as_float(r.z << 16); s[5] += __uint_as_float(r.z & 0xFFFF0000u);
      s[6] += __uint_as_float(r.w << 16); s[7] += __uint_as_float(r.w & 0xFFFF0000u);
    }
    const float inv = 1.f/15.f;
    uint4 o;
    o.x = (unsigned)f2bf(s[0]*inv) | ((unsigned)f2bf(s[1]*inv) << 16);
    o.y = (unsigned)f2bf(s[2]*inv) | ((unsigned)f2bf(s[3]*inv) << 16);
    o.z = (unsigned)f2bf(s[4]*inv) | ((unsigned)f2bf(s[5]*inv) << 16);
    o.w = (unsigned)f2bf(s[6]*inv) | ((unsigned)f2bf(s[7]*inv) << 16);
    *(uint4*)(dst + nn*CCP + c8) = o;
  }
}

// ------------- conv layer 2/3 fully fused (agg + agg + MFMA + pool) --------
// Exact R14 version (1024 threads, 16 waves, no kn staging).
__global__ __launch_bounds__(1024) void conv_fused_kernel(
    const unsigned short* __restrict__ hin,
    const int* __restrict__ knn,
    const unsigned short* __restrict__ Wpk,
    const float* __restrict__ bias,
    unsigned short* __restrict__ hout,
    float* __restrict__ gf, int poff){
  __shared__ unsigned short bufh[MM*CCP];
  __shared__ unsigned short bufa[MM*CCP];
  __shared__ float smean[4][CC], smax[4][CC];
  const int g   = blockIdx.x;
  const int tid = threadIdx.x;
  const int* kn_graph = knn + (size_t)g*MM*KNN;

  {
    const uint4* src = (const uint4*)(hin + (size_t)g*MM*CC);
    for (int e=tid; e<MM*CC/8; e+=1024){
      int row = e >> 4, ch = e & 15;
      *(uint4*)(bufh + row*CCP + ch*8) = src[e];
    }
  }
  __syncthreads();

  agg_lds(bufh, bufa, kn_graph, tid);   // a1 = agg(h)
  __syncthreads();

  const int wv   = tid >> 6, lane = tid & 63;
  const int n    = lane & 15, q = lane >> 4;
  const int rows0 = (wv & 7)*32;
  const int cols0 = (wv >> 3)*64;

  f32x4 acc[2][4];
#pragma unroll
  for (int i=0;i<2;i++)
#pragma unroll
    for (int t=0;t<4;t++) acc[i][t] = (f32x4){0.f,0.f,0.f,0.f};

#pragma unroll
  for (int ck=0; ck<8; ck++){
    const unsigned short* A = (ck < 4) ? bufh : bufa;
    const int kc = ck & 3;
    const unsigned short* ab = A + (rows0 + n)*CCP + kc*32 + q*8;
    bf16x8 af[2];
#pragma unroll
    for (int i=0;i<2;i++) af[i] = *(const bf16x8*)(ab + i*16*CCP);
    const unsigned short* wb = Wpk + ((size_t)(ck*4 + q)*CC + cols0 + n)*8;
    bf16x8 bf[4];
#pragma unroll
    for (int t=0;t<4;t++) bf[t] = *(const bf16x8*)(wb + t*16*8);
#pragma unroll
    for (int i=0;i<2;i++)
#pragma unroll
      for (int t=0;t<4;t++)
        acc[i][t] = __builtin_amdgcn_mfma_f32_16x16x32_bf16(af[i], bf[t], acc[i][t], 0, 0, 0);
  }
  __syncthreads();

  agg_lds(bufa, bufh, kn_graph, tid);   // a2 = agg(a1), overwrites bufh
  __syncthreads();

#pragma unroll
  for (int ck=8; ck<12; ck++){
    const int kc = ck & 3;
    const unsigned short* ab = bufh + (rows0 + n)*CCP + kc*32 + q*8;
    bf16x8 af[2];
#pragma unroll
    for (int i=0;i<2;i++) af[i] = *(const bf16x8*)(ab + i*16*CCP);
    const unsigned short* wb = Wpk + ((size_t)(ck*4 + q)*CC + cols0 + n)*8;
    bf16x8 bf[4];
#pragma unroll
    for (int t=0;t<4;t++) bf[t] = *(const bf16x8*)(wb + t*16*8);
#pragma unroll
    for (int i=0;i<2;i++)
#pragma unroll
      for (int t=0;t<4;t++)
        acc[i][t] = __builtin_amdgcn_mfma_f32_16x16x32_bf16(af[i], bf[t], acc[i][t], 0, 0, 0);
  }

  float bv[4];
#pragma unroll
  for (int t=0;t<4;t++) bv[t] = bias[cols0 + t*16 + n];
#pragma unroll
  for (int i=0;i<2;i++){
#pragma unroll
    for (int t=0;t<4;t++){
#pragma unroll
      for (int r=0;r<4;r++){
        int row = rows0 + i*16 + q*4 + r;
        int col = cols0 + t*16 + n;
        unsigned short o = f2bf(lrelu(acc[i][t][r] + bv[t]));
        hout[(size_t)(g*MM + row)*CC + col] = o;
        bufa[row*CCP + col] = o;
      }
    }
  }
  __syncthreads();

  {
    const int c = tid & 127, grp = (tid >> 7) & 3;
    if (tid < 512){
      float s = 0.f, mx = -FINF;
      for (int m=grp*64; m<grp*64+64; m++){
        float v = bf2f(bufa[m*CCP + c]);
        s += v; mx = fmaxf(mx, v);
      }
      smean[grp][c] = s; smax[grp][c] = mx;
    }
    __syncthreads();
    if (tid < 128){
      float s  = smean[0][c] + smean[1][c] + smean[2][c] + smean[3][c];
      float mx = fmaxf(fmaxf(smax[0][c], smax[1][c]), fmaxf(smax[2][c], smax[3][c]));
      gf[(size_t)g*C2 + poff + c]      = s * (1.f/MM);
      gf[(size_t)g*C2 + poff + CC + c] = mx;
    }
  }
}

// ------------------------------------------------------ batchnorm (stats) ---
__global__ __launch_bounds__(256) void bnstats_kernel(const float* __restrict__ g,
                                                      const float* __restrict__ gamma,
                                                      const float* __restrict__ beta,
                                                      float* __restrict__ scb,
                                                      float* __restrict__ shb){
  __shared__ float ssum[4][64], ssq[4][64];
  const int cl = threadIdx.x & 63, rg = threadIdx.x >> 6;
  const int c  = blockIdx.x*64 + cl;
  float s=0.f, q=0.f;
  for (int r=rg*64; r<rg*64+64; r++){
    float v = g[(size_t)r*C2 + c];
    s += v; q += v*v;
  }
  ssum[rg][cl]=s; ssq[rg][cl]=q;
  __syncthreads();
  if (rg == 0){
    s = ssum[0][cl]+ssum[1][cl]+ssum[2][cl]+ssum[3][cl];
    q = ssq [0][cl]+ssq [1][cl]+ssq [2][cl]+ssq [3][cl];
    float mu  = s * (1.f/NB);
    float var = q * (1.f/NB) - mu*mu;
    float sc  = rsqrtf(var + 1e-5f) * gamma[c];
    scb[c] = sc;
    shb[c] = beta[c] - mu*sc;
  }
}

// -------------------------------------------------- MLP (wave-K-split GEMM) -
// R16: 512 threads / 8 waves per block, K-chunk 96 (3 kt per wave). LDS
// 74 KB -> 2 blocks/CU = 16 waves/CU (was 6 at 256 thr/4 waves, 1.5 blk/CU:
// global W-stage latency had almost nothing co-resident to hide it). 8-way
// fp32 partial combine p1..p7 (summation order changes -> small fp32 drift;
// bf16 conv path untouched).
__global__ __launch_bounds__(512) void mlp_gemm_kernel(
    const float* __restrict__ A, const float* __restrict__ W,
    const float* __restrict__ bias,
    const float* __restrict__ scb, const float* __restrict__ shb, int affine,
    float* __restrict__ out){
  __shared__ float Ws[8][32][64];   // 64 KB
  __shared__ float At[8][32][10];   // 10 KB
  const int tid  = threadIdx.x;
  const int ks   = tid >> 6, lane = tid & 63;
  const int colq = lane & 15, rp = lane >> 4;
  const int col0 = blockIdx.x * 64;
  const int row0 = blockIdx.y * 8;

  float a00=0.f,a01=0.f,a02=0.f,a03=0.f;
  float a10=0.f,a11=0.f,a12=0.f,a13=0.f;

  for (int kt=0; kt<3; kt++){
    const int kc0 = ks*96 + kt*32;
#pragma unroll
    for (int i=0;i<8;i++){
      int idx = i*256 + lane*4;
      int kr = idx >> 6, cc = idx & 63;
      *(float4*)(&Ws[ks][kr][cc]) =
          *(const float4*)(W + (size_t)(kc0+kr)*C2 + col0 + cc);
    }
    {
      int row = lane >> 3, kq = lane & 7;
      float4 a = *(const float4*)(A + (size_t)(row0+row)*C2 + kc0 + kq*4);
      if (affine){
        float4 s4 = *(const float4*)(scb + kc0 + kq*4);
        float4 h4 = *(const float4*)(shb + kc0 + kq*4);
        a.x = a.x*s4.x + h4.x; a.y = a.y*s4.y + h4.y;
        a.z = a.z*s4.z + h4.z; a.w = a.w*s4.w + h4.w;
      }
      At[ks][kq*4+0][row] = a.x;
      At[ks][kq*4+1][row] = a.y;
      At[ks][kq*4+2][row] = a.z;
      At[ks][kq*4+3][row] = a.w;
    }
    __builtin_amdgcn_wave_barrier();
#pragma unroll 8
    for (int kk=0;kk<32;kk++){
      float4 w = *(const float4*)(&Ws[ks][kk][colq*4]);
      float b0 = At[ks][kk][rp*2+0];
      float b1 = At[ks][kk][rp*2+1];
      a00 += b0*w.x; a01 += b0*w.y; a02 += b0*w.z; a03 += b0*w.w;
      a10 += b1*w.x; a11 += b1*w.y; a12 += b1*w.z; a13 += b1*w.w;
    }
    __builtin_amdgcn_wave_barrier();
  }

  if (ks > 0){
    float* part = &Ws[ks][0][0];
    *(float4*)(part + (rp*2+0)*64 + colq*4) = make_float4(a00,a01,a02,a03);
    *(float4*)(part + (rp*2+1)*64 + colq*4) = make_float4(a10,a11,a12,a13);
  }
  __syncthreads();
  if (ks == 0){
    float4 bv = *(const float4*)(bias + col0 + colq*4);
    float accr[2][4] = {{a00,a01,a02,a03},{a10,a11,a12,a13}};
#pragma unroll
    for (int r=0;r<2;r++){
      int off = (rp*2+r)*64 + colq*4;
      float sx = accr[r][0], sy = accr[r][1], sz = accr[r][2], sw = accr[r][3];
#pragma unroll
      for (int pw=1; pw<8; pw++){
        float4 pp = *(const float4*)(&Ws[pw][0][0] + off);
        sx += pp.x; sy += pp.y; sz += pp.z; sw += pp.w;
      }
      float4 o;
      o.x = lrelu(sx + bv.x);
      o.y = lrelu(sy + bv.y);
      o.z = lrelu(sz + bv.z);
      o.w = lrelu(sw + bv.w);
      *(float4*)(out + (size_t)(row0 + rp*2 + r)*C2 + col0 + colq*4) = o;
    }
  }
}

// ------------------------------------------------------------- final layer --
__global__ __launch_bounds__(64) void final_kernel(const float* __restrict__ g,
                                                   const float* __restrict__ Wo,
                                                   const float* __restrict__ bo,
                                                   float* __restrict__ out){
  int i = blockIdx.x*64 + threadIdx.x;
  if (i >= NB*NL) return;
  int r = i / NL, c = i - r*NL;
  const float* gr = g + (size_t)r*C2;
  float acc = bo[c];
  for (int k=0;k<C2;k++) acc += gr[k]*Wo[k*NL + c];
  if (c < 2) acc = tanhf(acc);
  out[i] = acc;
}

// ------------------------------------------------------------------ launch --
extern "C" void kernel_launch(void* const* d_in, const int* in_sizes, int n_in,
                              void* d_out, int out_size, void* d_ws, size_t ws_size,
                              hipStream_t stream){
  const float* x   = (const float*)d_in[0];
  const float* Wc1 = (const float*)d_in[1];
  const float* bc1 = (const float*)d_in[2];
  const float* Wc2 = (const float*)d_in[3];
  const float* bc2 = (const float*)d_in[4];
  const float* Wc3 = (const float*)d_in[5];
  const float* bc3 = (const float*)d_in[6];
  const float* bng = (const float*)d_in[7];
  const float* bnb = (const float*)d_in[8];
  const float* W1  = (const float*)d_in[9];
  const float* b1  = (const float*)d_in[10];
  const float* W2  = (const float*)d_in[11];
  const float* b2  = (const float*)d_in[12];
  const float* W3  = (const float*)d_in[13];
  const float* b3  = (const float*)d_in[14];
  const float* W4  = (const float*)d_in[15];
  const float* b4  = (const float*)d_in[16];
  const float* W5  = (const float*)d_in[17];
  const float* b5  = (const float*)d_in[18];
  const float* Wo  = (const float*)d_in[19];
  const float* bo  = (const float*)d_in[20];

  char* ws = (char*)d_ws;
  size_t o = 0;
  int*            knn  = (int*)           (ws + o); o += (size_t)NN*KNN*4;
  unsigned short* h0   = (unsigned short*)(ws + o); o += (size_t)NN*CC*2;
  unsigned short* h3   = (unsigned short*)(ws + o); o += (size_t)NN*CC*2;
  float*          gf   = (float*)         (ws + o); o += (size_t)NB*C2*4;
  float*          gt   = (float*)         (ws + o); o += (size_t)NB*C2*4;
  unsigned short* Wpk2 = (unsigned short*)(ws + o); o += (size_t)3*CC*CC*2;
  unsigned short* Wpk3 = (unsigned short*)(ws + o); o += (size_t)3*CC*CC*2;
  float*          scb  = (float*)         (ws + o); o += (size_t)C2*4;
  float*          shb  = (float*)         (ws + o); o += (size_t)C2*4;

  knn_kernel<<<NB*64, 256, 0, stream>>>(x, knn);
  packW_kernel<<<384, 256, 0, stream>>>(Wc2, Wc3, Wpk2, Wpk3);

  layer1_fused_kernel<<<NB, 256, 0, stream>>>(x, knn, Wc1, bc1, h0, gf);
  conv_fused_kernel<<<NB, 1024, 0, stream>>>(h0, knn, Wpk2, bc2, h3, gf, 2*CC);
  conv_fused_kernel<<<NB, 1024, 0, stream>>>(h3, knn, Wpk3, bc3, h0, gf, 4*CC);

  bnstats_kernel<<<12, 256, 0, stream>>>(gf, bng, bnb, scb, shb);

  dim3 mgrid(12, 32);
  mlp_gemm_kernel<<<mgrid, 512, 0, stream>>>(gf, W1, b1, scb, shb, 1, gt);
  mlp_gemm_kernel<<<mgrid, 512, 0, stream>>>(gt, W2, b2, nullptr, nullptr, 0, gf);
  mlp_gemm_kernel<<<mgrid, 512, 0, stream>>>(gf, W3, b3, nullptr, nullptr, 0, gt);
  mlp_gemm_kernel<<<mgrid, 512, 0, stream>>>(gt, W4, b4, nullptr, nullptr, 0, gf);
  mlp_gemm_kernel<<<mgrid, 512, 0, stream>>>(gf, W5, b5, nullptr, nullptr, 0, gt);

  final_kernel<<<12, 64, 0, stream>>>(gt, Wo, bo, (float*)d_out);
}

// Round 17
// 337.650 us; speedup vs baseline: 1.0547x; 1.0281x over previous
//
#include <hip/hip_runtime.h>
#include <cstdint>
#include <cmath>

#define NB 256      // graphs (B)
#define MM 256      // nodes per graph
#define NN (NB*MM)  // 65536 nodes
#define KNN 15
#define FIN 7
#define CC 128
#define CCP 152     // padded LDS row stride (shorts): 304B = 76 dwords ≡ 12 (mod 32)
                    // -> MFMA A-frag 16-lane phases tile all 32 banks 2x (free);
                    // agg row reads stay 64-consecutive-dword (free). R12-16 used
                    // 136 (≡4): 4-way conflicts, 3.02M SQ_LDS_BANK_CONFLICT.
#define C2 768
#define NL 3
#define FINF 3.4e38f

__device__ __forceinline__ float lrelu(float v){ return v > 0.f ? v : 0.01f*v; }

__device__ __forceinline__ unsigned short f2bf(float f){
  unsigned u = __float_as_uint(f);
  return (unsigned short)((u + 0x7FFFu + ((u >> 16) & 1u)) >> 16);
}
__device__ __forceinline__ float bf2f(unsigned short h){
  return __uint_as_float(((unsigned)h) << 16);
}

__device__ __forceinline__ int mbcnt64(unsigned long long m){
  return (int)__builtin_amdgcn_mbcnt_hi((unsigned)(m >> 32),
              __builtin_amdgcn_mbcnt_lo((unsigned)m, 0u));
}

typedef short bf16x8 __attribute__((ext_vector_type(8)));
typedef float f32x4  __attribute__((ext_vector_type(4)));

// ---------------------------------------------------------------- kNN -------
// Radix-select (R9: 143 -> 58 us). Parked: issue/SALU-bound, micro-variants
// neutral (R8) or negative (R4, R15-split).
__global__ __launch_bounds__(256) void knn_kernel(const float* __restrict__ x,
                                                  int* __restrict__ knn){
  __shared__ float4 pos[MM];
  __shared__ float  sq[MM];
  __shared__ unsigned skey[4][16];
  __shared__ int      sidx[4][16];
  const int g = blockIdx.x >> 6;
  const int t = threadIdx.x;
  const float* xr = x + (size_t)(g*MM + t)*FIN;
  float4 p = make_float4(xr[0], xr[1], xr[2], xr[3]);
  pos[t] = p;
  sq[t]  = p.x*p.x + p.y*p.y + p.z*p.z + p.w*p.w;
  __syncthreads();

  const int i    = (blockIdx.x & 63)*4 + (t >> 6);
  const int wv   = t >> 6;
  const int lane = t & 63;
  const float4 pi = pos[i];
  const float  sqi = sq[i];

  unsigned key[4];
#pragma unroll
  for (int q=0;q<4;q++){
    int j = q*64 + lane;
    float4 pj = pos[j];
    float dot = pi.x*pj.x + pi.y*pj.y + pi.z*pj.z + pi.w*pj.w;
    float d2  = sqi + sq[j] - 2.f*dot;
    unsigned u = __float_as_uint(d2);
    u = ((int)u < 0) ? ~u : (u ^ 0x80000000u);
    key[q] = (j == i) ? 0xFFFFFFFFu : u;
  }

  unsigned prefix = 0u;
#pragma unroll
  for (int bit=31; bit>=0; --bit){
    unsigned trial = prefix | (1u << bit);
    int c = __popcll(__ballot(key[0] < trial))
          + __popcll(__ballot(key[1] < trial))
          + __popcll(__ballot(key[2] < trial))
          + __popcll(__ballot(key[3] < trial));
    if (c < KNN) prefix = trial;
  }
  const unsigned K = prefix;

  int c_lt = __popcll(__ballot(key[0] < K)) + __popcll(__ballot(key[1] < K))
           + __popcll(__ballot(key[2] < K)) + __popcll(__ballot(key[3] < K));
  int need = KNN - c_lt;
  bool w[4];
  int eqbase = 0;
#pragma unroll
  for (int q=0;q<4;q++){
    unsigned long long em = __ballot(key[q] == K);
    int gr = eqbase + mbcnt64(em);
    w[q] = (key[q] < K) || ((key[q] == K) && (gr < need));
    eqbase += __popcll(em);
  }

  int base2 = 0;
#pragma unroll
  for (int q=0;q<4;q++){
    unsigned long long wm = __ballot(w[q]);
    int rk = mbcnt64(wm);
    if (w[q]){ skey[wv][base2+rk] = key[q]; sidx[wv][base2+rk] = q*64 + lane; }
    base2 += __popcll(wm);
  }
  __builtin_amdgcn_wave_barrier();

  if (lane < KNN){
    unsigned mk = skey[wv][lane]; int mi = sidx[wv][lane];
    int r = 0;
#pragma unroll
    for (int m=0;m<KNN;m++){
      unsigned ok = skey[wv][m]; int oi = sidx[wv][m];
      r += (ok < mk || (ok == mk && oi < mi)) ? 1 : 0;
    }
    knn[(size_t)(g*MM + i)*KNN + r] = g*MM + mi;
  }
}

// -------------------- layer 1 fused (agg7 x2 + conv1 + pool0) ---------------
__global__ __launch_bounds__(256) void layer1_fused_kernel(
    const float* __restrict__ x, const int* __restrict__ knn,
    const float* __restrict__ W, const float* __restrict__ b,
    unsigned short* __restrict__ out, float* __restrict__ gf){
  __shared__ float feat[MM][24];
  __shared__ float smean[4][CC], smax[4][CC];
  const int g = blockIdx.x, tid = threadIdx.x;
  for (int e=tid; e<MM*FIN; e+=256){
    int nn = e / FIN, f = e - nn*FIN;
    feat[nn][f] = x[(size_t)g*MM*FIN + e];
  }
  __syncthreads();
  {
    const int nn = tid;
    const int* kn = knn + (size_t)(g*MM + nn)*KNN;
    int loc[KNN];
#pragma unroll
    for (int k=0;k<KNN;k++) loc[k] = kn[k] & (MM-1);
#pragma unroll
    for (int c=0;c<FIN;c++){
      float s = 0.f;
#pragma unroll
      for (int k=0;k<KNN;k++) s += feat[loc[k]][c];
      feat[nn][FIN + c] = s * (1.f/15.f);
    }
    __syncthreads();
#pragma unroll
    for (int c=0;c<FIN;c++){
      float s = 0.f;
#pragma unroll
      for (int k=0;k<KNN;k++) s += feat[loc[k]][FIN + c];
      feat[nn][2*FIN + c] = s * (1.f/15.f);
    }
  }
  __syncthreads();
  const int c    = tid & 127;
  const int half = tid >> 7;
  float wcol[3*FIN];
#pragma unroll
  for (int t2=0;t2<3*FIN;t2++) wcol[t2] = W[t2*CC + c];
  const float bc = b[c];
  float ps[2] = {0.f, 0.f};
  float pm[2] = {-FINF, -FINF};
  for (int nn=half*128; nn<half*128+128; ++nn){
    float4 f0 = *(const float4*)(&feat[nn][0]);
    float4 f1 = *(const float4*)(&feat[nn][4]);
    float4 f2 = *(const float4*)(&feat[nn][8]);
    float4 f3 = *(const float4*)(&feat[nn][12]);
    float4 f4 = *(const float4*)(&feat[nn][16]);
    float4 f5 = *(const float4*)(&feat[nn][20]);
    float fv[21] = {f0.x,f0.y,f0.z,f0.w, f1.x,f1.y,f1.z,f1.w,
                    f2.x,f2.y,f2.z,f2.w, f3.x,f3.y,f3.z,f3.w,
                    f4.x,f4.y,f4.z,f4.w, f5.x};
    float acc = bc;
#pragma unroll
    for (int t2=0;t2<3*FIN;t2++) acc += fv[t2]*wcol[t2];
    unsigned short o = f2bf(lrelu(acc));
    out[(size_t)(g*MM + nn)*CC + c] = o;
    float v = bf2f(o);
    int lg = (nn >> 6) & 1;
    ps[lg] += v; pm[lg] = fmaxf(pm[lg], v);
  }
  smean[half*2+0][c] = ps[0]; smean[half*2+1][c] = ps[1];
  smax [half*2+0][c] = pm[0]; smax [half*2+1][c] = pm[1];
  __syncthreads();
  if (tid < 128){
    float s  = smean[0][c] + smean[1][c] + smean[2][c] + smean[3][c];
    float mx = fmaxf(fmaxf(smax[0][c], smax[1][c]), fmaxf(smax[2][c], smax[3][c]));
    gf[(size_t)g*C2 + c]      = s * (1.f/MM);
    gf[(size_t)g*C2 + CC + c] = mx;
  }
}

// ----------------------------------------------- pack W into B-frag order ---
__global__ void packW_kernel(const float* __restrict__ W2src,
                             const float* __restrict__ W3src,
                             unsigned short* __restrict__ W2dst,
                             unsigned short* __restrict__ W3dst){
  int idx = blockIdx.x*256 + threadIdx.x;
  if (idx >= 2*3*CC*CC) return;
  const float* Wsrc = (idx < 3*CC*CC) ? W2src : W3src;
  unsigned short* Wdst = (idx < 3*CC*CC) ? W2dst : W3dst;
  int e = (idx < 3*CC*CC) ? idx : idx - 3*CC*CC;
  int kg = e >> 7;
  int n  = e & 127;
  int ck = kg >> 5, q = (kg >> 3) & 3, j = kg & 7;
  Wdst[(((ck*4 + q)*CC) + n)*8 + j] = f2bf(Wsrc[e]);
}

// ---------------------- exact agg128 arithmetic, LDS->LDS (1024 threads) ----
__device__ __forceinline__ void agg_lds(const unsigned short* __restrict__ src,
                                        unsigned short* __restrict__ dst,
                                        const int* __restrict__ kn_graph,
                                        int tid){
  for (int it=0; it<4; ++it){
    int idx = it*1024 + tid;
    int nn  = idx >> 4;
    int c8  = (idx & 15) * 8;
    const int* kn = kn_graph + nn*KNN;
    float s[8];
#pragma unroll
    for (int e=0;e<8;e++) s[e]=0.f;
#pragma unroll
    for (int k=0;k<KNN;k++){
      int loc = kn[k] & (MM-1);
      uint4 r = *(const uint4*)(src + loc*CCP + c8);
      s[0] += __uint_as_float(r.x << 16); s[1] += __uint_as_float(r.x & 0xFFFF0000u);
      s[2] += __uint_as_float(r.y << 16); s[3] += __uint_as_float(r.y & 0xFFFF0000u);
      s[4] += __uint_as_float(r.z << 16); s[5] += __uint_as_float(r.z & 0xFFFF0000u);
      s[6] += __uint_as_float(r.w << 16); s[7] += __uint_as_float(r.w & 0xFFFF0000u);
    }
    const float inv = 1.f/15.f;
    uint4 o;
    o.x = (unsigned)f2bf(s[0]*inv) | ((unsigned)f2bf(s[1]*inv) << 16);
    o.y = (unsigned)f2bf(s[2]*inv) | ((unsigned)f2bf(s[3]*inv) << 16);
    o.z = (unsigned)f2bf(s[4]*inv) | ((unsigned)f2bf(s[5]*inv) << 16);
    o.w = (unsigned)f2bf(s[6]*inv) | ((unsigned)f2bf(s[7]*inv) << 16);
    *(uint4*)(dst + nn*CCP + c8) = o;
  }
}

// 4 consecutive MFMA K-chunks from one A buffer (order-preserving helper)
__device__ __forceinline__ void mfma_seg(const unsigned short* __restrict__ A,
                                         const unsigned short* __restrict__ Wpk,
                                         int ck0, int rows0, int cols0,
                                         int n, int q, f32x4 acc[2][4]){
#pragma unroll
  for (int cki=0; cki<4; cki++){
    const int ck = ck0 + cki;
    const int kc = ck & 3;
    const unsigned short* ab = A + (rows0 + n)*CCP + kc*32 + q*8;
    bf16x8 af[2];
#pragma unroll
    for (int i=0;i<2;i++) af[i] = *(const bf16x8*)(ab + i*16*CCP);
    const unsigned short* wb = Wpk + ((size_t)(ck*4 + q)*CC + cols0 + n)*8;
    bf16x8 bf[4];
#pragma unroll
    for (int t=0;t<4;t++) bf[t] = *(const bf16x8*)(wb + t*16*8);
#pragma unroll
    for (int i=0;i<2;i++)
#pragma unroll
      for (int t=0;t<4;t++)
        acc[i][t] = __builtin_amdgcn_mfma_f32_16x16x32_bf16(af[i], bf[t], acc[i][t], 0, 0, 0);
  }
}

// --------- conv layers 2 AND 3 fully fused (agg2 + MFMA + pool, twice) ------
// One block per graph, 1024 threads. Layer 2's bf16 output stays in LDS and
// feeds layer 3 directly: h3 and the layer-3 h-output NEVER touch global
// (~50 MB HBM saved + one full-device dispatch drain). Same f2bf-rounded
// 16-bit values flow through LDS as would have round-tripped -> bit-exact;
// per-layer MFMA order (h, a1, a2 x chunk asc) and agg/pool arithmetic
// unchanged. LDS: 2 x 76.0 KB bufs + 4 KB pool scratch = 159.7 KB (fits).
__global__ __launch_bounds__(1024) void conv23_fused_kernel(
    const unsigned short* __restrict__ hin,
    const int* __restrict__ knn,
    const unsigned short* __restrict__ Wpk2, const float* __restrict__ b2,
    const unsigned short* __restrict__ Wpk3, const float* __restrict__ b3,
    float* __restrict__ gf){
  __shared__ unsigned short bufh[MM*CCP];   // 77824 B
  __shared__ unsigned short bufa[MM*CCP];   // 77824 B
  __shared__ float smean[4][CC], smax[4][CC];
  const int g   = blockIdx.x;
  const int tid = threadIdx.x;
  const int* kn_graph = knn + (size_t)g*MM*KNN;

  // stage h (layer-1 output) -> bufh
  {
    const uint4* src = (const uint4*)(hin + (size_t)g*MM*CC);
    for (int e=tid; e<MM*CC/8; e+=1024){
      int row = e >> 4, ch = e & 15;
      *(uint4*)(bufh + row*CCP + ch*8) = src[e];
    }
  }
  __syncthreads();

  const int wv   = tid >> 6, lane = tid & 63;
  const int n    = lane & 15, q = lane >> 4;
  const int rows0 = (wv & 7)*32;
  const int cols0 = (wv >> 3)*64;

  f32x4 acc[2][4];

  // ================= layer 2 =================
  agg_lds(bufh, bufa, kn_graph, tid);   // a1_2 = agg(h)
  __syncthreads();
#pragma unroll
  for (int i=0;i<2;i++)
#pragma unroll
    for (int t=0;t<4;t++) acc[i][t] = (f32x4){0.f,0.f,0.f,0.f};
  mfma_seg(bufh, Wpk2, 0, rows0, cols0, n, q, acc);   // ck0-3 (h)
  mfma_seg(bufa, Wpk2, 4, rows0, cols0, n, q, acc);   // ck4-7 (a1)
  __syncthreads();
  agg_lds(bufa, bufh, kn_graph, tid);   // a2_2 = agg(a1), overwrites h
  __syncthreads();
  mfma_seg(bufh, Wpk2, 8, rows0, cols0, n, q, acc);   // ck8-11 (a2)
  // epilogue -> bufa (h3 stays in LDS)
  {
    float bv[4];
#pragma unroll
    for (int t=0;t<4;t++) bv[t] = b2[cols0 + t*16 + n];
#pragma unroll
    for (int i=0;i<2;i++)
#pragma unroll
      for (int t=0;t<4;t++)
#pragma unroll
        for (int r=0;r<4;r++){
          int row = rows0 + i*16 + q*4 + r;
          int col = cols0 + t*16 + n;
          bufa[row*CCP + col] = f2bf(lrelu(acc[i][t][r] + bv[t]));
        }
  }
  __syncthreads();
  // pool layer 2 (verbatim arithmetic)
  {
    const int c = tid & 127, grp = (tid >> 7) & 3;
    if (tid < 512){
      float s = 0.f, mx = -FINF;
      for (int m=grp*64; m<grp*64+64; m++){
        float v = bf2f(bufa[m*CCP + c]);
        s += v; mx = fmaxf(mx, v);
      }
      smean[grp][c] = s; smax[grp][c] = mx;
    }
    __syncthreads();
    if (tid < 128){
      float s  = smean[0][c] + smean[1][c] + smean[2][c] + smean[3][c];
      float mx = fmaxf(fmaxf(smax[0][c], smax[1][c]), fmaxf(smax[2][c], smax[3][c]));
      gf[(size_t)g*C2 + 2*CC + c]      = s * (1.f/MM);
      gf[(size_t)g*C2 + 2*CC + CC + c] = mx;
    }
  }
  __syncthreads();

  // ================= layer 3 (h3 = bufa) =================
  agg_lds(bufa, bufh, kn_graph, tid);   // a1_3 = agg(h3)
  __syncthreads();
#pragma unroll
  for (int i=0;i<2;i++)
#pragma unroll
    for (int t=0;t<4;t++) acc[i][t] = (f32x4){0.f,0.f,0.f,0.f};
  mfma_seg(bufa, Wpk3, 0, rows0, cols0, n, q, acc);   // ck0-3 (h3)
  mfma_seg(bufh, Wpk3, 4, rows0, cols0, n, q, acc);   // ck4-7 (a1_3)
  __syncthreads();
  agg_lds(bufh, bufa, kn_graph, tid);   // a2_3 = agg(a1_3), overwrites h3
  __syncthreads();
  mfma_seg(bufa, Wpk3, 8, rows0, cols0, n, q, acc);   // ck8-11 (a2_3)
  // epilogue -> bufh (no global h write needed; only the pool consumes it)
  {
    float bv[4];
#pragma unroll
    for (int t=0;t<4;t++) bv[t] = b3[cols0 + t*16 + n];
#pragma unroll
    for (int i=0;i<2;i++)
#pragma unroll
      for (int t=0;t<4;t++)
#pragma unroll
        for (int r=0;r<4;r++){
          int row = rows0 + i*16 + q*4 + r;
          int col = cols0 + t*16 + n;
          bufh[row*CCP + col] = f2bf(lrelu(acc[i][t][r] + bv[t]));
        }
  }
  __syncthreads();
  // pool layer 3
  {
    const int c = tid & 127, grp = (tid >> 7) & 3;
    if (tid < 512){
      float s = 0.f, mx = -FINF;
      for (int m=grp*64; m<grp*64+64; m++){
        float v = bf2f(bufh[m*CCP + c]);
        s += v; mx = fmaxf(mx, v);
      }
      smean[grp][c] = s; smax[grp][c] = mx;
    }
    __syncthreads();
    if (tid < 128){
      float s  = smean[0][c] + smean[1][c] + smean[2][c] + smean[3][c];
      float mx = fmaxf(fmaxf(smax[0][c], smax[1][c]), fmaxf(smax[2][c], smax[3][c]));
      gf[(size_t)g*C2 + 4*CC + c]      = s * (1.f/MM);
      gf[(size_t)g*C2 + 4*CC + CC + c] = mx;
    }
  }
}

// ------------------------------------------------------ batchnorm (stats) ---
__global__ __launch_bounds__(256) void bnstats_kernel(const float* __restrict__ g,
                                                      const float* __restrict__ gamma,
                                                      const float* __restrict__ beta,
                                                      float* __restrict__ scb,
                                                      float* __restrict__ shb){
  __shared__ float ssum[4][64], ssq[4][64];
  const int cl = threadIdx.x & 63, rg = threadIdx.x >> 6;
  const int c  = blockIdx.x*64 + cl;
  float s=0.f, q=0.f;
  for (int r=rg*64; r<rg*64+64; r++){
    float v = g[(size_t)r*C2 + c];
    s += v; q += v*v;
  }
  ssum[rg][cl]=s; ssq[rg][cl]=q;
  __syncthreads();
  if (rg == 0){
    s = ssum[0][cl]+ssum[1][cl]+ssum[2][cl]+ssum[3][cl];
    q = ssq [0][cl]+ssq [1][cl]+ssq [2][cl]+ssq [3][cl];
    float mu  = s * (1.f/NB);
    float var = q * (1.f/NB) - mu*mu;
    float sc  = rsqrtf(var + 1e-5f) * gamma[c];
    scb[c] = sc;
    shb[c] = beta[c] - mu*sc;
  }
}

// -------------------------------------------------- MLP (wave-K-split GEMM) -
__global__ __launch_bounds__(512) void mlp_gemm_kernel(
    const float* __restrict__ A, const float* __restrict__ W,
    const float* __restrict__ bias,
    const float* __restrict__ scb, const float* __restrict__ shb, int affine,
    float* __restrict__ out){
  __shared__ float Ws[8][32][64];   // 64 KB
  __shared__ float At[8][32][10];   // 10 KB
  const int tid  = threadIdx.x;
  const int ks   = tid >> 6, lane = tid & 63;
  const int colq = lane & 15, rp = lane >> 4;
  const int col0 = blockIdx.x * 64;
  const int row0 = blockIdx.y * 8;

  float a00=0.f,a01=0.f,a02=0.f,a03=0.f;
  float a10=0.f,a11=0.f,a12=0.f,a13=0.f;

  for (int kt=0; kt<3; kt++){
    const int kc0 = ks*96 + kt*32;
#pragma unroll
    for (int i=0;i<8;i++){
      int idx = i*256 + lane*4;
      int kr = idx >> 6, cc = idx & 63;
      *(float4*)(&Ws[ks][kr][cc]) =
          *(const float4*)(W + (size_t)(kc0+kr)*C2 + col0 + cc);
    }
    {
      int row = lane >> 3, kq = lane & 7;
      float4 a = *(const float4*)(A + (size_t)(row0+row)*C2 + kc0 + kq*4);
      if (affine){
        float4 s4 = *(const float4*)(scb + kc0 + kq*4);
        float4 h4 = *(const float4*)(shb + kc0 + kq*4);
        a.x = a.x*s4.x + h4.x; a.y = a.y*s4.y + h4.y;
        a.z = a.z*s4.z + h4.z; a.w = a.w*s4.w + h4.w;
      }
      At[ks][kq*4+0][row] = a.x;
      At[ks][kq*4+1][row] = a.y;
      At[ks][kq*4+2][row] = a.z;
      At[ks][kq*4+3][row] = a.w;
    }
    __builtin_amdgcn_wave_barrier();
#pragma unroll 8
    for (int kk=0;kk<32;kk++){
      float4 w = *(const float4*)(&Ws[ks][kk][colq*4]);
      float b0 = At[ks][kk][rp*2+0];
      float b1 = At[ks][kk][rp*2+1];
      a00 += b0*w.x; a01 += b0*w.y; a02 += b0*w.z; a03 += b0*w.w;
      a10 += b1*w.x; a11 += b1*w.y; a12 += b1*w.z; a13 += b1*w.w;
    }
    __builtin_amdgcn_wave_barrier();
  }

  if (ks > 0){
    float* part = &Ws[ks][0][0];
    *(float4*)(part + (rp*2+0)*64 + colq*4) = make_float4(a00,a01,a02,a03);
    *(float4*)(part + (rp*2+1)*64 + colq*4) = make_float4(a10,a11,a12,a13);
  }
  __syncthreads();
  if (ks == 0){
    float4 bv = *(const float4*)(bias + col0 + colq*4);
    float accr[2][4] = {{a00,a01,a02,a03},{a10,a11,a12,a13}};
#pragma unroll
    for (int r=0;r<2;r++){
      int off = (rp*2+r)*64 + colq*4;
      float sx = accr[r][0], sy = accr[r][1], sz = accr[r][2], sw = accr[r][3];
#pragma unroll
      for (int pw=1; pw<8; pw++){
        float4 pp = *(const float4*)(&Ws[pw][0][0] + off);
        sx += pp.x; sy += pp.y; sz += pp.z; sw += pp.w;
      }
      float4 o;
      o.x = lrelu(sx + bv.x);
      o.y = lrelu(sy + bv.y);
      o.z = lrelu(sz + bv.z);
      o.w = lrelu(sw + bv.w);
      *(float4*)(out + (size_t)(row0 + rp*2 + r)*C2 + col0 + colq*4) = o;
    }
  }
}

// ------------------------------------------------------------- final layer --
__global__ __launch_bounds__(64) void final_kernel(const float* __restrict__ g,
                                                   const float* __restrict__ Wo,
                                                   const float* __restrict__ bo,
                                                   float* __restrict__ out){
  int i = blockIdx.x*64 + threadIdx.x;
  if (i >= NB*NL) return;
  int r = i / NL, c = i - r*NL;
  const float* gr = g + (size_t)r*C2;
  float acc = bo[c];
  for (int k=0;k<C2;k++) acc += gr[k]*Wo[k*NL + c];
  if (c < 2) acc = tanhf(acc);
  out[i] = acc;
}

// ------------------------------------------------------------------ launch --
extern "C" void kernel_launch(void* const* d_in, const int* in_sizes, int n_in,
                              void* d_out, int out_size, void* d_ws, size_t ws_size,
                              hipStream_t stream){
  const float* x   = (const float*)d_in[0];
  const float* Wc1 = (const float*)d_in[1];
  const float* bc1 = (const float*)d_in[2];
  const float* Wc2 = (const float*)d_in[3];
  const float* bc2 = (const float*)d_in[4];
  const float* Wc3 = (const float*)d_in[5];
  const float* bc3 = (const float*)d_in[6];
  const float* bng = (const float*)d_in[7];
  const float* bnb = (const float*)d_in[8];
  const float* W1  = (const float*)d_in[9];
  const float* b1  = (const float*)d_in[10];
  const float* W2  = (const float*)d_in[11];
  const float* b2  = (const float*)d_in[12];
  const float* W3  = (const float*)d_in[13];
  const float* b3  = (const float*)d_in[14];
  const float* W4  = (const float*)d_in[15];
  const float* b4  = (const float*)d_in[16];
  const float* W5  = (const float*)d_in[17];
  const float* b5  = (const float*)d_in[18];
  const float* Wo  = (const float*)d_in[19];
  const float* bo  = (const float*)d_in[20];

  char* ws = (char*)d_ws;
  size_t o = 0;
  int*            knn  = (int*)           (ws + o); o += (size_t)NN*KNN*4;
  unsigned short* h0   = (unsigned short*)(ws + o); o += (size_t)NN*CC*2;
  float*          gf   = (float*)         (ws + o); o += (size_t)NB*C2*4;
  float*          gt   = (float*)         (ws + o); o += (size_t)NB*C2*4;
  unsigned short* Wpk2 = (unsigned short*)(ws + o); o += (size_t)3*CC*CC*2;
  unsigned short* Wpk3 = (unsigned short*)(ws + o); o += (size_t)3*CC*CC*2;
  float*          scb  = (float*)         (ws + o); o += (size_t)C2*4;
  float*          shb  = (float*)         (ws + o); o += (size_t)C2*4;

  knn_kernel<<<NB*64, 256, 0, stream>>>(x, knn);
  packW_kernel<<<384, 256, 0, stream>>>(Wc2, Wc3, Wpk2, Wpk3);

  layer1_fused_kernel<<<NB, 256, 0, stream>>>(x, knn, Wc1, bc1, h0, gf);
  conv23_fused_kernel<<<NB, 1024, 0, stream>>>(h0, knn, Wpk2, bc2, Wpk3, bc3, gf);

  bnstats_kernel<<<12, 256, 0, stream>>>(gf, bng, bnb, scb, shb);

  dim3 mgrid(12, 32);
  mlp_gemm_kernel<<<mgrid, 512, 0, stream>>>(gf, W1, b1, scb, shb, 1, gt);
  mlp_gemm_kernel<<<mgrid, 512, 0, stream>>>(gt, W2, b2, nullptr, nullptr, 0, gf);
  mlp_gemm_kernel<<<mgrid, 512, 0, stream>>>(gf, W3, b3, nullptr, nullptr, 0, gt);
  mlp_gemm_kernel<<<mgrid, 512, 0, stream>>>(gt, W4, b4, nullptr, nullptr, 0, gf);
  mlp_gemm_kernel<<<mgrid, 512, 0, stream>>>(gf, W5, b5, nullptr, nullptr, 0, gt);

  final_kernel<<<12, 64, 0, stream>>>(gt, Wo, bo, (float*)d_out);
}